// Round 12
// baseline (129.723 us; speedup 1.0000x reference)
//
#include <hip/hip_runtime.h>
#include <stdint.h>

#define D 128
#define TM 64
#define GRID 512        // 2 blocks/CU * 256 CU
#define NTHREADS 512    // 8 waves/block
#define PPW 9           // pp row stride (f32), conflict-free

typedef float f32x4 __attribute__((ext_vector_type(4)));
typedef short s16x8 __attribute__((ext_vector_type(8)));
typedef uint32_t u32x2 __attribute__((ext_vector_type(2)));

__device__ __forceinline__ short f2bf(float f) {
    union { float f; uint32_t u; } v; v.f = f;
    return (short)((v.u + 0x7fffu + ((v.u >> 16) & 1u)) >> 16);   // RNE
}
__device__ __forceinline__ uint32_t cvt_pk_bf16(float lo, float hi) {
    uint32_t r;
    asm("v_cvt_pk_bf16_f32 %0, %1, %2" : "=v"(r) : "v"(lo), "v"(hi));
    return r;
}

__global__ __launch_bounds__(NTHREADS, 2)   // VGPR<=128 -> 16 waves/CU
void gate_agg_kernel(const float* __restrict__ X,
                     const int* __restrict__ bidx,
                     const float* __restrict__ W1,
                     const float* __restrict__ b1,
                     const float* __restrict__ W2,
                     const float* __restrict__ b2,
                     float* __restrict__ out,
                     int NT)
{
    // 4 bf16 tile buffers (pair-parity x 2 tiles) - avoids stage-vs-phase3 race
    __shared__ short xt[4][TM * D];    // 64 KB
    __shared__ float pp[2][64 * PPW];  // gate partials per tile-in-pair
    __shared__ u32x2 gid[2][TM];       // {gate bits, seg} per tile-in-pair

    const int tid = threadIdx.x;
    const int l = tid & 63;
    const int w = tid >> 6;            // 0..7
    const int l15 = l & 15;
    const int lk = l >> 4;

    // W1 col-slice to regs: wave w owns h-cols 16w..16w+15 (16 VGPR)
    s16x8 bfr[4];
    #pragma unroll
    for (int kt = 0; kt < 4; ++kt)
        #pragma unroll
        for (int e = 0; e < 8; ++e)
            bfr[kt][e] = f2bf(W1[(kt * 32 + lk * 8 + e) * D + 16 * w + l15]);

    float b1v[4], w2v[4];
    #pragma unroll
    for (int r = 0; r < 4; ++r) {
        b1v[r] = b1[16 * w + lk * 4 + r];
        w2v[r] = W2[16 * w + lk * 4 + r];
    }
    const float b2s = b2[0];

    // balanced contiguous tile range
    const int q = NT / GRID, rem = NT % GRID;
    int t0, t1;
    if ((int)blockIdx.x < rem) { t0 = blockIdx.x * (q + 1); t1 = t0 + q + 1; }
    else { t0 = rem * (q + 1) + ((int)blockIdx.x - rem) * q; t1 = t0 + q; }

    float acc3[2] = {0.f, 0.f};
    int cur = -1;

    // prologue: depth-2 prefetch
    f32x4 vA[4], vB[4];
    int ridxA = 0, ridxB = 0;
    if (t0 < t1) {
        const float* xg = X + (size_t)t0 * TM * D;
        #pragma unroll
        for (int j = 0; j < 4; ++j) vA[j] = *(const f32x4*)(xg + (size_t)(j * 512 + tid) * 4);
        if (l < 8) ridxA = bidx[(size_t)t0 * TM + 8 * w + l];
    }
    if (t0 + 1 < t1) {
        const float* xg = X + (size_t)(t0 + 1) * TM * D;
        #pragma unroll
        for (int j = 0; j < 4; ++j) vB[j] = *(const f32x4*)(xg + (size_t)(j * 512 + tid) * 4);
        if (l < 8) ridxB = bidx[(size_t)(t0 + 1) * TM + 8 * w + l];
    }

#define STAGE(V, SB) {                                                           \
        _Pragma("unroll")                                                        \
        for (int j = 0; j < 4; ++j) {                                            \
            int qc = j * 512 + tid;                                              \
            int row = qc >> 5, cq = qc & 31;                                     \
            int c2 = cq >> 1, h = cq & 1;                                        \
            u32x2 wv;                                                            \
            wv[0] = cvt_pk_bf16(V[j][0], V[j][1]);                               \
            wv[1] = cvt_pk_bf16(V[j][2], V[j][3]);                               \
            *(u32x2*)((char*)xt + (SB) * 16384 + row * 256 +                     \
                      ((c2 ^ (row & 15)) << 4) + h * 8) = wv;                    \
        }                                                                        \
    }

#define ISSUE(V, RIDX, TT) {                                                     \
        const float* xg = X + (size_t)(TT) * TM * D;                             \
        _Pragma("unroll")                                                        \
        for (int j = 0; j < 4; ++j)                                              \
            V[j] = *(const f32x4*)(xg + (size_t)(j * 512 + tid) * 4);            \
        if (l < 8) RIDX = bidx[(size_t)(TT) * TM + 8 * w + l];                   \
    }

#define MFMA_PP(SB, PI) {                                                        \
        f32x4 acc[4];                                                            \
        acc[0] = (f32x4)0.f; acc[1] = (f32x4)0.f;                                \
        acc[2] = (f32x4)0.f; acc[3] = (f32x4)0.f;                                \
        _Pragma("unroll")                                                        \
        for (int kt = 0; kt < 4; ++kt) {                                         \
            const int kc = kt * 4 + lk;                                          \
            _Pragma("unroll")                                                    \
            for (int nf = 0; nf < 4; ++nf) {                                     \
                const int R = nf * 16 + l15;                                     \
                s16x8 xb = *(const s16x8*)((const char*)xt + (SB) * 16384 +      \
                            R * 256 + ((kc ^ l15) << 4));                        \
                acc[nf] = __builtin_amdgcn_mfma_f32_16x16x32_bf16(bfr[kt], xb, acc[nf], 0, 0, 0); \
            }                                                                    \
        }                                                                        \
        _Pragma("unroll")                                                        \
        for (int nf = 0; nf < 4; ++nf) {                                         \
            float s = 0.f;                                                       \
            _Pragma("unroll")                                                    \
            for (int r = 0; r < 4; ++r) {                                        \
                float h = acc[nf][r] + b1v[r];                                   \
                h = fmaxf(h, 0.f);                                               \
                s = fmaf(h, w2v[r], s);                                          \
            }                                                                    \
            s += __shfl_xor(s, 16, 64);                                          \
            s += __shfl_xor(s, 32, 64);                                          \
            if (l < 16) pp[PI][(nf * 16 + l) * PPW + w] = s;                     \
        }                                                                        \
    }

#define GATE(PI, RCUR) {                                                         \
        if (l < 8) {                                                             \
            const int node = 8 * w + l;                                          \
            float s = 0.f;                                                       \
            _Pragma("unroll")                                                    \
            for (int c = 0; c < 8; ++c) s += pp[PI][node * PPW + c];             \
            float g = 1.f / (1.f + __expf(-(s + b2s)));                          \
            u32x2 gi; gi[0] = __float_as_uint(g); gi[1] = (uint32_t)(RCUR);      \
            gid[PI][node] = gi;                                                  \
        }                                                                        \
    }

#define PHASE3(SB, PI) {                                                         \
        _Pragma("unroll")                                                        \
        for (int r = 0; r < 8; ++r) {                                            \
            const int row = 8 * w + r;                                           \
            u32x2 gi = gid[PI][row];                                             \
            const int seg = (int)gi[1];                                          \
            const float g = __uint_as_float(gi[0]);                              \
            if (seg != cur) {                                                    \
                if (cur >= 0) {                                                  \
                    atomicAdd(out + (size_t)cur * D + 2 * l,     acc3[0]);       \
                    atomicAdd(out + (size_t)cur * D + 2 * l + 1, acc3[1]);       \
                }                                                                \
                acc3[0] = 0.f; acc3[1] = 0.f; cur = seg;                         \
            }                                                                    \
            uint32_t xv = *(const uint32_t*)((const char*)xt + (SB) * 16384 +    \
                           row * 256 + ((((l >> 2) ^ (row & 15)) << 4)) + (l & 3) * 4); \
            acc3[0] = fmaf(g, __uint_as_float(xv << 16),         acc3[0]);       \
            acc3[1] = fmaf(g, __uint_as_float(xv & 0xffff0000u), acc3[1]);       \
        }                                                                        \
    }

    int t = t0, cb = 0;                      // cb = pair-parity buffer base (0 or 2)
    while (t + 1 < t1) {                     // ---- pair iterations ----
        STAGE(vA, cb);
        STAGE(vB, cb + 1);
        const int rA = ridxA, rB = ridxB;
        if (t + 2 < t1) ISSUE(vA, ridxA, t + 2);
        if (t + 3 < t1) ISSUE(vB, ridxB, t + 3);
        asm volatile("s_waitcnt lgkmcnt(0)" ::: "memory");
        __builtin_amdgcn_s_barrier();                    // B_stage
        __builtin_amdgcn_sched_barrier(0);

        MFMA_PP(cb, 0);
        MFMA_PP(cb + 1, 1);
        asm volatile("s_waitcnt lgkmcnt(0)" ::: "memory");
        __builtin_amdgcn_s_barrier();                    // B_pp
        __builtin_amdgcn_sched_barrier(0);

        GATE(0, rA);
        GATE(1, rB);
        asm volatile("s_waitcnt lgkmcnt(0)" ::: "memory");  // same-wave gid vis
        __builtin_amdgcn_sched_barrier(0);

        PHASE3(cb, 0);
        PHASE3(cb + 1, 1);

        t += 2; cb ^= 2;
    }
    if (t < t1) {                            // ---- single-tile tail (in vA) ----
        STAGE(vA, cb);
        const int rA = ridxA;
        asm volatile("s_waitcnt lgkmcnt(0)" ::: "memory");
        __builtin_amdgcn_s_barrier();
        __builtin_amdgcn_sched_barrier(0);
        MFMA_PP(cb, 0);
        asm volatile("s_waitcnt lgkmcnt(0)" ::: "memory");
        __builtin_amdgcn_s_barrier();
        __builtin_amdgcn_sched_barrier(0);
        GATE(0, rA);
        asm volatile("s_waitcnt lgkmcnt(0)" ::: "memory");
        __builtin_amdgcn_sched_barrier(0);
        PHASE3(cb, 0);
    }
#undef STAGE
#undef ISSUE
#undef MFMA_PP
#undef GATE
#undef PHASE3

    if (cur >= 0) {
        atomicAdd(out + (size_t)cur * D + 2 * l,     acc3[0]);
        atomicAdd(out + (size_t)cur * D + 2 * l + 1, acc3[1]);
    }
}

extern "C" void kernel_launch(void* const* d_in, const int* in_sizes, int n_in,
                              void* d_out, int out_size, void* d_ws, size_t ws_size,
                              hipStream_t stream) {
    const float* X    = (const float*)d_in[0];
    const int*   bidx = (const int*)d_in[1];
    const float* W1   = (const float*)d_in[2];
    const float* b1   = (const float*)d_in[3];
    const float* W2   = (const float*)d_in[4];
    const float* b2   = (const float*)d_in[5];
    float* out = (float*)d_out;

    const int N  = in_sizes[0] / D;      // 1,000,000
    const int NT = N / TM;               // 15,625 tiles

    hipMemsetAsync(d_out, 0, (size_t)out_size * sizeof(float), stream);
    gate_agg_kernel<<<GRID, NTHREADS, 0, stream>>>(X, bidx, W1, b1, W2, b2, out, NT);
}

// Round 13
// 118.414 us; speedup vs baseline: 1.0955x; 1.0955x over previous
//
#include <hip/hip_runtime.h>
#include <stdint.h>

#define D 128
#define TM 64
#define GRID 512        // 2 blocks/CU * 256 CU
#define NTHREADS 512    // 8 waves/block
#define PPW 9           // pp row stride (f32), conflict-free

typedef float f32x4 __attribute__((ext_vector_type(4)));
typedef short s16x8 __attribute__((ext_vector_type(8)));
typedef uint32_t u32x2 __attribute__((ext_vector_type(2)));

__device__ __forceinline__ short f2bf(float f) {
    union { float f; uint32_t u; } v; v.f = f;
    return (short)((v.u + 0x7fffu + ((v.u >> 16) & 1u)) >> 16);   // RNE
}
__device__ __forceinline__ uint32_t cvt_pk_bf16(float lo, float hi) {
    uint32_t r;
    asm("v_cvt_pk_bf16_f32 %0, %1, %2" : "=v"(r) : "v"(lo), "v"(hi));
    return r;
}

__global__ __launch_bounds__(NTHREADS, 2)   // VGPR<=128 -> 16 waves/CU
void gate_agg_kernel(const float* __restrict__ X,
                     const int* __restrict__ bidx,
                     const float* __restrict__ W1,
                     const float* __restrict__ b1,
                     const float* __restrict__ W2,
                     const float* __restrict__ b2,
                     float* __restrict__ out,
                     int NT)
{
    __shared__ short xt[3][TM * D];    // bf16 tiles, 3 rotating buffers, 48 KB
    __shared__ float pp[2][64 * PPW];  // gate partials, tile-parity dbuf
    __shared__ u32x2 gid[TM];          // {gate bits, seg}; same-wave use

    const int tid = threadIdx.x;
    const int l = tid & 63;
    const int w = tid >> 6;            // 0..7
    const int l15 = l & 15;
    const int lk = l >> 4;

    // W1 col-slice to regs: wave w owns h-cols 16w..16w+15 (16 VGPR)
    s16x8 bfr[4];
    #pragma unroll
    for (int kt = 0; kt < 4; ++kt)
        #pragma unroll
        for (int e = 0; e < 8; ++e)
            bfr[kt][e] = f2bf(W1[(kt * 32 + lk * 8 + e) * D + 16 * w + l15]);

    float b1v[4], w2v[4];
    #pragma unroll
    for (int r = 0; r < 4; ++r) {
        b1v[r] = b1[16 * w + lk * 4 + r];
        w2v[r] = W2[16 * w + lk * 4 + r];
    }
    const float b2s = b2[0];

    // balanced contiguous tile range
    const int q = NT / GRID, rem = NT % GRID;
    int t0, t1;
    if ((int)blockIdx.x < rem) { t0 = blockIdx.x * (q + 1); t1 = t0 + q + 1; }
    else { t0 = rem * (q + 1) + ((int)blockIdx.x - rem) * q; t1 = t0 + q; }

    float acc3[2] = {0.f, 0.f};
    int cur = -1;

    // prologue: depth-2 register prefetch
    f32x4 vA[4], vB[4];
    int ridxA = 0, ridxB = 0;
    if (t0 < t1) {
        const float* xg = X + (size_t)t0 * TM * D;
        #pragma unroll
        for (int j = 0; j < 4; ++j) vA[j] = *(const f32x4*)(xg + (size_t)(j * 512 + tid) * 4);
        if (l < 8) ridxA = bidx[(size_t)t0 * TM + 8 * w + l];
    }
    if (t0 + 1 < t1) {
        const float* xg = X + (size_t)(t0 + 1) * TM * D;
        #pragma unroll
        for (int j = 0; j < 4; ++j) vB[j] = *(const f32x4*)(xg + (size_t)(j * 512 + tid) * 4);
        if (l < 8) ridxB = bidx[(size_t)(t0 + 1) * TM + 8 * w + l];
    }

#define STAGE(V, CB) {                                                           \
        _Pragma("unroll")                                                        \
        for (int j = 0; j < 4; ++j) {                                            \
            int qc = j * 512 + tid;                                              \
            int row = qc >> 5, cq = qc & 31;                                     \
            int c2 = cq >> 1, h = cq & 1;                                        \
            u32x2 wv;                                                            \
            wv[0] = cvt_pk_bf16(V[j][0], V[j][1]);                               \
            wv[1] = cvt_pk_bf16(V[j][2], V[j][3]);                               \
            *(u32x2*)((char*)xt + (CB) * 16384 + row * 256 +                     \
                      ((c2 ^ (row & 15)) << 4) + h * 8) = wv;                    \
        }                                                                        \
    }

#define MFMA_PP(CB, PI) {                                                        \
        f32x4 acc[4];                                                            \
        acc[0] = (f32x4)0.f; acc[1] = (f32x4)0.f;                                \
        acc[2] = (f32x4)0.f; acc[3] = (f32x4)0.f;                                \
        _Pragma("unroll")                                                        \
        for (int kt = 0; kt < 4; ++kt) {                                         \
            const int kc = kt * 4 + lk;                                          \
            _Pragma("unroll")                                                    \
            for (int nf = 0; nf < 4; ++nf) {                                     \
                const int R = nf * 16 + l15;                                     \
                s16x8 xb = *(const s16x8*)((const char*)xt + (CB) * 16384 +      \
                            R * 256 + ((kc ^ l15) << 4));                        \
                acc[nf] = __builtin_amdgcn_mfma_f32_16x16x32_bf16(bfr[kt], xb, acc[nf], 0, 0, 0); \
            }                                                                    \
        }                                                                        \
        _Pragma("unroll")                                                        \
        for (int nf = 0; nf < 4; ++nf) {                                         \
            float s = 0.f;                                                       \
            _Pragma("unroll")                                                    \
            for (int r = 0; r < 4; ++r) {                                        \
                float h = acc[nf][r] + b1v[r];                                   \
                h = fmaxf(h, 0.f);                                               \
                s = fmaf(h, w2v[r], s);                                          \
            }                                                                    \
            s += __shfl_xor(s, 16, 64);                                          \
            s += __shfl_xor(s, 32, 64);                                          \
            if (l < 16) pp[PI][(nf * 16 + l) * PPW + w] = s;                     \
        }                                                                        \
    }

#define GATE(PI, RIDXP) {                                                        \
        if (l < 8) {                                                             \
            const int node = 8 * w + l;                                          \
            float s = 0.f;                                                       \
            _Pragma("unroll")                                                    \
            for (int c = 0; c < 8; ++c) s += pp[PI][node * PPW + c];             \
            float g = 1.f / (1.f + __expf(-(s + b2s)));                          \
            u32x2 gi; gi[0] = __float_as_uint(g); gi[1] = (uint32_t)(RIDXP);     \
            gid[node] = gi;                                                      \
        }                                                                        \
    }

#define PHASE3(CB) {                                                             \
        _Pragma("unroll")                                                        \
        for (int r = 0; r < 8; ++r) {                                            \
            const int row = 8 * w + r;                                           \
            u32x2 gi = gid[row];                                                 \
            const int seg = (int)gi[1];                                          \
            const float g = __uint_as_float(gi[0]);                              \
            if (seg != cur) {                                                    \
                if (cur >= 0) {                                                  \
                    atomicAdd(out + (size_t)cur * D + 2 * l,     acc3[0]);       \
                    atomicAdd(out + (size_t)cur * D + 2 * l + 1, acc3[1]);       \
                }                                                                \
                acc3[0] = 0.f; acc3[1] = 0.f; cur = seg;                         \
            }                                                                    \
            uint32_t xv = *(const uint32_t*)((const char*)xt + (CB) * 16384 +    \
                           row * 256 + ((((l >> 2) ^ (row & 15)) << 4)) + (l & 3) * 4); \
            acc3[0] = fmaf(g, __uint_as_float(xv << 16),         acc3[0]);       \
            acc3[1] = fmaf(g, __uint_as_float(xv & 0xffff0000u), acc3[1]);       \
        }                                                                        \
    }

    // BODY for tile t: stage(t), barrier, MFMA+pp(t), gate+phase3(t-1)
#define BODY(V, RIDX) {                                                          \
        STAGE(V, cb);                                                            \
        const int ridx_cur = RIDX;                                               \
        if (t + 2 < t1) {                          /* depth-2 refill */          \
            const float* xg = X + (size_t)(t + 2) * TM * D;                      \
            _Pragma("unroll")                                                    \
            for (int j = 0; j < 4; ++j)                                          \
                V[j] = *(const f32x4*)(xg + (size_t)(j * 512 + tid) * 4);        \
            if (l < 8) RIDX = bidx[(size_t)(t + 2) * TM + 8 * w + l];            \
        }                                                                        \
        asm volatile("s_waitcnt lgkmcnt(0)" ::: "memory");                       \
        __builtin_amdgcn_s_barrier();              /* the ONLY barrier */        \
        __builtin_amdgcn_sched_barrier(0);                                       \
        MFMA_PP(cb, t & 1);                                                      \
        if (t > t0) {                                                            \
            GATE((t - 1) & 1, ridxPrev);                                         \
            asm volatile("s_waitcnt lgkmcnt(0)" ::: "memory");                   \
            PHASE3(cbPrev);                                                      \
        }                                                                        \
        ridxPrev = ridx_cur;                                                     \
        cbPrev = cb;                                                             \
        cb = (cb == 2) ? 0 : cb + 1;                                             \
    }

    int t = t0, cb = 0, cbPrev = 0, ridxPrev = 0;
    while (t < t1) {
        BODY(vA, ridxA); ++t; if (t >= t1) break;
        BODY(vB, ridxB); ++t;
    }
    // epilogue: gate+phase3 for the last tile
    if (t1 > t0) {
        asm volatile("s_waitcnt lgkmcnt(0)" ::: "memory");
        __builtin_amdgcn_s_barrier();              // publish last pp
        __builtin_amdgcn_sched_barrier(0);
        GATE((t1 - 1) & 1, ridxPrev);
        asm volatile("s_waitcnt lgkmcnt(0)" ::: "memory");
        PHASE3(cbPrev);
    }
#undef STAGE
#undef MFMA_PP
#undef GATE
#undef PHASE3
#undef BODY

    if (cur >= 0) {
        atomicAdd(out + (size_t)cur * D + 2 * l,     acc3[0]);
        atomicAdd(out + (size_t)cur * D + 2 * l + 1, acc3[1]);
    }
}

extern "C" void kernel_launch(void* const* d_in, const int* in_sizes, int n_in,
                              void* d_out, int out_size, void* d_ws, size_t ws_size,
                              hipStream_t stream) {
    const float* X    = (const float*)d_in[0];
    const int*   bidx = (const int*)d_in[1];
    const float* W1   = (const float*)d_in[2];
    const float* b1   = (const float*)d_in[3];
    const float* W2   = (const float*)d_in[4];
    const float* b2   = (const float*)d_in[5];
    float* out = (float*)d_out;

    const int N  = in_sizes[0] / D;      // 1,000,000
    const int NT = N / TM;               // 15,625 tiles

    hipMemsetAsync(d_out, 0, (size_t)out_size * sizeof(float), stream);
    gate_agg_kernel<<<GRID, NTHREADS, 0, stream>>>(X, bidx, W1, b1, W2, b2, out, NT);
}

// Round 14
// 111.133 us; speedup vs baseline: 1.1673x; 1.0655x over previous
//
#include <hip/hip_runtime.h>
#include <stdint.h>

#define D 128
#define TM 64
#define GRID 512        // 2 blocks/CU * 256 CU
#define NTHREADS 512    // 8 waves/block
#define PPW 9           // pp row stride (f32), gcd(9,32)=1 -> conflict-free

typedef float f32x4 __attribute__((ext_vector_type(4)));
typedef short s16x8 __attribute__((ext_vector_type(8)));
typedef uint32_t u32x2 __attribute__((ext_vector_type(2)));

__device__ __forceinline__ short f2bf(float f) {
    union { float f; uint32_t u; } v; v.f = f;
    return (short)((v.u + 0x7fffu + ((v.u >> 16) & 1u)) >> 16);   // RNE
}
__device__ __forceinline__ uint32_t cvt_pk_bf16(float lo, float hi) {
    uint32_t r;
    asm("v_cvt_pk_bf16_f32 %0, %1, %2" : "=v"(r) : "v"(lo), "v"(hi));
    return r;
}

__global__ __launch_bounds__(NTHREADS, 2)   // 2 blocks/CU -> 16 waves/CU, VGPR<=128
void gate_agg_kernel(const float* __restrict__ X,
                     const int* __restrict__ bidx,
                     const float* __restrict__ W1,
                     const float* __restrict__ b1,
                     const float* __restrict__ W2,
                     const float* __restrict__ b2,
                     float* __restrict__ out,
                     int NT)
{
    __shared__ short xt[2][TM * D];    // bf16 tiles, chunk-swizzled, 2 x 16 KB
    __shared__ float pp[64 * PPW];     // gate partials [node][wave 0..7]
    __shared__ u32x2 gid[TM];          // {gate bits, seg}; per-wave 8-row slice

    const int tid = threadIdx.x;
    const int l = tid & 63;
    const int w = tid >> 6;            // 0..7 (8 waves)
    const int l15 = l & 15;
    const int lk = l >> 4;

    // ---- W1 col-slice to regs: wave w owns h-cols 16w..16w+15 (16 VGPR)
    // A-frag (MFMA 1st operand): lane holds W1[k = kt*32+lk*8+e][16w + l15]
    s16x8 bfr[4];
    #pragma unroll
    for (int kt = 0; kt < 4; ++kt)
        #pragma unroll
        for (int e = 0; e < 8; ++e)
            bfr[kt][e] = f2bf(W1[(kt * 32 + lk * 8 + e) * D + 16 * w + l15]);

    // per-lane bias/W2 for hcol = 16w + lk*4 + r   (D-row index)
    float b1v[4], w2v[4];
    #pragma unroll
    for (int r = 0; r < 4; ++r) {
        b1v[r] = b1[16 * w + lk * 4 + r];
        w2v[r] = W2[16 * w + lk * 4 + r];
    }
    const float b2s = b2[0];

    // balanced contiguous tile range
    const int q = NT / GRID, rem = NT % GRID;
    int t0, t1;
    if ((int)blockIdx.x < rem) { t0 = blockIdx.x * (q + 1); t1 = t0 + q + 1; }
    else { t0 = rem * (q + 1) + ((int)blockIdx.x - rem) * q; t1 = t0 + q; }

    // phase-3: wave w owns rows 8w..8w+7; lane owns cols 2l, 2l+1
    float acc3[2] = {0.f, 0.f};
    int cur = -1;

    // ---- prologue: depth-2 register prefetch (4 x f32x4 per thread per tile)
    f32x4 vA[4], vB[4];
    int ridxA = 0, ridxB = 0;
    if (t0 < t1) {
        const float* xg = X + (size_t)t0 * TM * D;
        #pragma unroll
        for (int j = 0; j < 4; ++j) vA[j] = *(const f32x4*)(xg + (size_t)(j * 512 + tid) * 4);
        if (l < 8) ridxA = bidx[(size_t)t0 * TM + 8 * w + l];
    }
    if (t0 + 1 < t1) {
        const float* xg = X + (size_t)(t0 + 1) * TM * D;
        #pragma unroll
        for (int j = 0; j < 4; ++j) vB[j] = *(const f32x4*)(xg + (size_t)(j * 512 + tid) * 4);
        if (l < 8) ridxB = bidx[(size_t)(t0 + 1) * TM + 8 * w + l];
    }

#define BODY(V, RIDX, PB)                                                        \
    {                                                                            \
        /* stage V -> bf16 swizzled xt[PB]; vmcnt waits per-use (counted) */     \
        _Pragma("unroll")                                                        \
        for (int j = 0; j < 4; ++j) {                                            \
            int qc = j * 512 + tid;                                              \
            int row = qc >> 5, cq = qc & 31;                                     \
            int c2 = cq >> 1, h = cq & 1;                                        \
            u32x2 wv;                                                            \
            wv[0] = cvt_pk_bf16(V[j][0], V[j][1]);                               \
            wv[1] = cvt_pk_bf16(V[j][2], V[j][3]);                               \
            *(u32x2*)((char*)xt[PB] + row * 256 + ((c2 ^ (row & 15)) << 4) + h * 8) = wv; \
        }                                                                        \
        const int ridx_cur = RIDX;                                               \
        /* depth-2: issue t+2 into just-freed regs (in flight all iteration) */  \
        if (t + 2 < t1) {                                                        \
            const float* xg = X + (size_t)(t + 2) * TM * D;                      \
            _Pragma("unroll")                                                    \
            for (int j = 0; j < 4; ++j)                                          \
                V[j] = *(const f32x4*)(xg + (size_t)(j * 512 + tid) * 4);        \
            if (l < 8) RIDX = bidx[(size_t)(t + 2) * TM + 8 * w + l];            \
        }                                                                        \
        asm volatile("s_waitcnt lgkmcnt(0)" ::: "memory");                       \
        __builtin_amdgcn_s_barrier();                    /* B_stage */           \
        __builtin_amdgcn_sched_barrier(0);                                       \
        /* phase 1: D[hcol][node]; A = W1-slice (regs), B = X from LDS */        \
        f32x4 acc[4];                                                            \
        acc[0] = (f32x4)0.f; acc[1] = (f32x4)0.f;                                \
        acc[2] = (f32x4)0.f; acc[3] = (f32x4)0.f;                                \
        _Pragma("unroll")                                                        \
        for (int kt = 0; kt < 4; ++kt) {                                         \
            const int kc = kt * 4 + lk;                                          \
            _Pragma("unroll")                                                    \
            for (int nf = 0; nf < 4; ++nf) {                                     \
                const int R = nf * 16 + l15;                                     \
                s16x8 xb = *(const s16x8*)((const char*)xt[PB] + R * 256 + ((kc ^ l15) << 4)); \
                acc[nf] = __builtin_amdgcn_mfma_f32_16x16x32_bf16(bfr[kt], xb, acc[nf], 0, 0, 0); \
            }                                                                    \
        }                                                                        \
        /* phase 2a: partial logits over wave's 16 hcols; reduce lk (2 shfl) */  \
        _Pragma("unroll")                                                        \
        for (int nf = 0; nf < 4; ++nf) {                                         \
            float s = 0.f;                                                       \
            _Pragma("unroll")                                                    \
            for (int r = 0; r < 4; ++r) {                                        \
                float h = acc[nf][r] + b1v[r];                                   \
                h = fmaxf(h, 0.f);                                               \
                s = fmaf(h, w2v[r], s);                                          \
            }                                                                    \
            s += __shfl_xor(s, 16, 64);                                          \
            s += __shfl_xor(s, 32, 64);                                          \
            if (l < 16) pp[(nf * 16 + l) * PPW + w] = s;                         \
        }                                                                        \
        asm volatile("s_waitcnt lgkmcnt(0)" ::: "memory");                       \
        __builtin_amdgcn_s_barrier();                    /* B_pp */              \
        __builtin_amdgcn_sched_barrier(0);                                       \
        /* phase 2b: lanes<8 finish gate for own rows 8w+l (8 waves cover 64) */ \
        if (l < 8) {                                                             \
            const int node = 8 * w + l;                                          \
            float s = 0.f;                                                       \
            _Pragma("unroll")                                                    \
            for (int c = 0; c < 8; ++c) s += pp[node * PPW + c];                 \
            float g = 1.f / (1.f + __expf(-(s + b2s)));                          \
            u32x2 gi; gi[0] = __float_as_uint(g); gi[1] = (uint32_t)ridx_cur;    \
            gid[node] = gi;                                                      \
        }                                                                        \
        asm volatile("s_waitcnt lgkmcnt(0)" ::: "memory");  /* same-wave vis */  \
        __builtin_amdgcn_sched_barrier(0);                                       \
        /* phase 3: segmented accumulate over wave's 8 rows (bf16 from LDS) */   \
        _Pragma("unroll")                                                        \
        for (int r = 0; r < 8; ++r) {                                            \
            const int row = 8 * w + r;                                           \
            u32x2 gi = gid[row];                                                 \
            const int seg = (int)gi[1];                                          \
            const float g = __uint_as_float(gi[0]);                              \
            if (seg != cur) {                                                    \
                if (cur >= 0) {                                                  \
                    atomicAdd(out + (size_t)cur * D + 2 * l,     acc3[0]);       \
                    atomicAdd(out + (size_t)cur * D + 2 * l + 1, acc3[1]);       \
                }                                                                \
                acc3[0] = 0.f; acc3[1] = 0.f; cur = seg;                         \
            }                                                                    \
            uint32_t xv = *(const uint32_t*)((const char*)xt[PB] + row * 256 +   \
                           ((((l >> 2) ^ (row & 15)) << 4)) + (l & 3) * 4);      \
            acc3[0] = fmaf(g, __uint_as_float(xv << 16),         acc3[0]);       \
            acc3[1] = fmaf(g, __uint_as_float(xv & 0xffff0000u), acc3[1]);       \
        }                                                                        \
    }

    int t = t0;
    while (t < t1) {
        BODY(vA, ridxA, 0);
        ++t; if (t >= t1) break;
        BODY(vB, ridxB, 1);
        ++t;
    }
#undef BODY

    if (cur >= 0) {
        atomicAdd(out + (size_t)cur * D + 2 * l,     acc3[0]);
        atomicAdd(out + (size_t)cur * D + 2 * l + 1, acc3[1]);
    }
}

extern "C" void kernel_launch(void* const* d_in, const int* in_sizes, int n_in,
                              void* d_out, int out_size, void* d_ws, size_t ws_size,
                              hipStream_t stream) {
    const float* X    = (const float*)d_in[0];
    const int*   bidx = (const int*)d_in[1];
    const float* W1   = (const float*)d_in[2];
    const float* b1   = (const float*)d_in[3];
    const float* W2   = (const float*)d_in[4];
    const float* b2   = (const float*)d_in[5];
    float* out = (float*)d_out;

    const int N  = in_sizes[0] / D;      // 1,000,000
    const int NT = N / TM;               // 15,625 tiles

    hipMemsetAsync(d_out, 0, (size_t)out_size * sizeof(float), stream);
    gate_agg_kernel<<<GRID, NTHREADS, 0, stream>>>(X, bidx, W1, b1, W2, b2, out, NT);
}